// Round 5
// baseline (259.797 us; speedup 1.0000x reference)
//
#include <hip/hip_runtime.h>
#include <hip/hip_bf16.h>
#include <math.h>

typedef __bf16 bf16;
typedef bf16 bf16x8 __attribute__((ext_vector_type(8)));
typedef float floatx4 __attribute__((ext_vector_type(4)));

#define MFMA16(a, b, c) __builtin_amdgcn_mfma_f32_16x16x32_bf16(a, b, c, 0, 0, 0)

constexpr int Bb = 2, Ss = 2048, Hh = 16, Dd = 128;
constexpr float SCALE = 0.08838834764831845f;  // 1/sqrt(128), folded into Q

// Split-K schedule: per bh, 40 units. qt<4 direct; qt>=4 split into 2-4 chunks
// of 10..16 k-tiles (k-tile = 32 keys). U_S/U_E are k-tile ranges.
__constant__ int U_QT[40] = {0,1,2,3, 4,4, 5,5, 6,6, 7,7, 8,8,8, 9,9,9, 10,10,10,
                             11,11,11, 12,12,12,12, 13,13,13,13, 14,14,14,14, 15,15,15,15};
__constant__ int U_S[40]  = {0,0,0,0, 0,10, 0,12, 0,14, 0,16, 0,12,24, 0,14,27, 0,15,30,
                             0,16,32, 0,13,26,39, 0,14,28,42, 0,15,30,45, 0,16,32,48};
__constant__ int U_E[40]  = {4,8,12,16, 10,20, 12,24, 14,28, 16,32, 12,24,36, 14,27,40,
                             15,30,44, 16,32,48, 13,26,39,52, 14,28,42,56, 15,30,45,60,
                             16,32,48,64};
// Reduce tables: for qt=4..15, first split-slot (unit-4) and chunk count.
__constant__ int RS0[12] = {0,2,4,6,8,11,14,17,20,24,28,32};
__constant__ int RN[12]  = {2,2,2,2,3,3,3,3,4,4,4,4};

// ---------------------------------------------------------------------------
// Kernel 1: pack qkv (fp32) -> MFMA-fragment-ordered bf16 blobs (unchanged).
// ---------------------------------------------------------------------------
__global__ __launch_bounds__(256) void prep_pack(const float* __restrict__ qkv,
                                                 bf16* __restrict__ QP,
                                                 bf16* __restrict__ KP,
                                                 bf16* __restrict__ VP) {
  __shared__ bf16 Vt[64 * 136];

  const int tid = threadIdx.x;
  const int w = tid >> 6, lane = tid & 63, quad = lane >> 4, l15 = lane & 15;
  const int qt = blockIdx.x, bh = blockIdx.y;
  const int b = bh >> 4, h = bh & 15;
  const int q0 = qt * 64;
  const size_t rs = (size_t)3 * Hh * Dd;
  const float* base = qkv + (size_t)b * Ss * rs + (size_t)h * Dd;

  for (int idx = tid; idx < 64 * 32; idx += 256) {
    const int row = idx >> 5;
    const int c4 = (idx & 31) << 2;
    const float* p = base + (size_t)(q0 + row) * rs + 2 * Hh * Dd + c4;
    float4 x = *(const float4*)p;
    bf16* d = Vt + row * 136 + c4;
    d[0] = (bf16)x.x; d[1] = (bf16)x.y; d[2] = (bf16)x.z; d[3] = (bf16)x.w;
  }

  {
    bf16* blob = QP + (size_t)(bh * 32 + qt) * 8192;
    const float* src = base + (size_t)(q0 + 4 * l15 + w) * rs;
    for (int kk = 0; kk < 4; ++kk) {
      const float* s8 = src + kk * 32 + quad * 8;
      float4 x0 = *(const float4*)s8, x1 = *(const float4*)(s8 + 4);
      bf16x8 f;
      f[0] = (bf16)(x0.x * SCALE); f[1] = (bf16)(x0.y * SCALE);
      f[2] = (bf16)(x0.z * SCALE); f[3] = (bf16)(x0.w * SCALE);
      f[4] = (bf16)(x1.x * SCALE); f[5] = (bf16)(x1.y * SCALE);
      f[6] = (bf16)(x1.z * SCALE); f[7] = (bf16)(x1.w * SCALE);
      *(bf16x8*)(blob + (size_t)(((w * 4 + kk) * 4 + quad) * 16 + l15) * 8) = f;
    }
  }

  const int ktg = qt * 2 + (w >> 1);
  {
    const int c = w & 1;
    bf16* blob = KP + (size_t)(bh * 64 + ktg) * 4096;
    const float* src = base + (size_t)(ktg * 32 + c * 16 + l15) * rs + Hh * Dd;
    for (int kk = 0; kk < 4; ++kk) {
      const float* s8 = src + kk * 32 + quad * 8;
      float4 x0 = *(const float4*)s8, x1 = *(const float4*)(s8 + 4);
      bf16x8 f;
      f[0] = (bf16)x0.x; f[1] = (bf16)x0.y; f[2] = (bf16)x0.z; f[3] = (bf16)x0.w;
      f[4] = (bf16)x1.x; f[5] = (bf16)x1.y; f[6] = (bf16)x1.z; f[7] = (bf16)x1.w;
      *(bf16x8*)(blob + (size_t)(((c * 4 + kk) * 4 + quad) * 16 + l15) * 8) = f;
    }
  }

  __syncthreads();

  {
    bf16* blob = VP + (size_t)(bh * 64 + ktg) * 4096;
    const int kloc = (w >> 1) * 32;
    for (int ti = 0; ti < 4; ++ti) {
      const int t = (w & 1) * 4 + ti;
      const int d = t * 16 + l15;
      bf16x8 f;
      for (int j = 0; j < 8; ++j) f[j] = Vt[(kloc + quad * 8 + j) * 136 + d];
      *(bf16x8*)(blob + (size_t)((t * 4 + quad) * 16 + l15) * 8) = f;
    }
  }
}

__device__ __forceinline__ void cp1k(const bf16* src, bf16* dst, int lane) {
  __builtin_amdgcn_global_load_lds(
      (__attribute__((address_space(1))) void*)(src + lane * 8),
      (__attribute__((address_space(3))) void*)dst, 16, 0, 0);
}

// ---------------------------------------------------------------------------
// Kernel 2 (split-K): block = unit (bh, qt, k-chunk). 4 waves x 2 m-tiles =
// 128 q-rows. Direct units write final O; split units write bf16 partial O +
// fp32 partial l (no-max softmax => partials are additive).
// ---------------------------------------------------------------------------
__global__ __launch_bounds__(256, 3) void attn_fwd_s(const bf16* __restrict__ QP,
                                                     const bf16* __restrict__ KP,
                                                     const bf16* __restrict__ VP,
                                                     float* __restrict__ out,
                                                     bf16* __restrict__ PO,
                                                     float* __restrict__ PL) {
  __shared__ bf16 Kl[2][4096];
  __shared__ bf16 Vl[2][4096];
  __shared__ bf16 Pl[4 * 32 * 40];

  const int tid = threadIdx.x;
  const int w = tid >> 6, lane = tid & 63, quad = lane >> 4, l15 = lane & 15;
  const int u = blockIdx.x;
  const int bh = blockIdx.y;
  const int b = bh >> 4, h = bh & 15;
  const int qt = U_QT[u];
  const int ks = U_S[u], ke = U_E[u];
  const int q0 = qt * 128;

  bf16x8 qf[2][4];
  for (int m = 0; m < 2; ++m) {
    const bf16* qp = QP + (size_t)(bh * 32 + 2 * qt + m) * 8192;
    for (int kk = 0; kk < 4; ++kk)
      qf[m][kk] = *(const bf16x8*)(qp + (size_t)(((w * 4 + kk) * 4 + quad) * 16 + l15) * 8);
  }

  floatx4 acc_o[2][8];
  for (int m = 0; m < 2; ++m)
    for (int t = 0; t < 8; ++t) acc_o[m][t] = (floatx4){0.f, 0.f, 0.f, 0.f};
  float l_part[2][4] = {{0.f, 0.f, 0.f, 0.f}, {0.f, 0.f, 0.f, 0.f}};

  const size_t bh64 = (size_t)bh * 64;
  bf16* pw = &Pl[w * 1280];

  auto stage = [&](int kt, int nb) {
    const bf16* kblob = KP + (bh64 + kt) * 4096;
    const bf16* vblob = VP + (bh64 + kt) * 4096;
    if (w < 2) {
      for (int i = 0; i < 4; ++i) {
        const int g = w * 4 + i;
        cp1k(kblob + g * 512, &Kl[nb][g * 512], lane);
      }
    } else {
      for (int i = 0; i < 4; ++i) {
        const int g = (w - 2) * 4 + i;
        cp1k(vblob + g * 512, &Vl[nb][g * 512], lane);
      }
    }
  };

  stage(ks, 0);
  __syncthreads();

  for (int it = 0, kt = ks; kt < ke; ++kt, ++it) {
    const int nb = it & 1;
    if (kt + 1 < ke) stage(kt + 1, nb ^ 1);

    const bool do0 = (kt <= 4 * qt + 1);
    const bool mask0 = (kt >= 4 * qt);
    const bool mask1 = (kt >= 4 * qt + 2);
    const int kbase = kt * 32;

    floatx4 s0[2], s1[2];
    s0[0] = s0[1] = s1[0] = s1[1] = (floatx4){0.f, 0.f, 0.f, 0.f};
    for (int c = 0; c < 2; ++c)
      for (int kk = 0; kk < 4; ++kk) {
        bf16x8 bfrag = *(const bf16x8*)(&Kl[nb][((c * 4 + kk) * 64 + lane) * 8]);
        if (do0) s0[c] = MFMA16(qf[0][kk], bfrag, s0[c]);
        s1[c] = MFMA16(qf[1][kk], bfrag, s1[c]);
      }

    if (do0) {
      float p[2][4];
      if (mask0) {
        for (int c = 0; c < 2; ++c) {
          const int colg = kbase + c * 16 + l15;
          for (int r = 0; r < 4; ++r) {
            const int rowg = q0 + 4 * (quad * 4 + r) + w;
            p[c][r] = __expf((colg > rowg) ? -10000.f : s0[c][r]);
          }
        }
      } else {
        for (int c = 0; c < 2; ++c)
          for (int r = 0; r < 4; ++r) p[c][r] = __expf(s0[c][r]);
      }
      for (int r = 0; r < 4; ++r) l_part[0][r] += p[0][r] + p[1][r];
      for (int c = 0; c < 2; ++c)
        for (int r = 0; r < 4; ++r)
          pw[(quad * 4 + r) * 40 + c * 16 + l15] = (bf16)p[c][r];
    }
    {
      float p[2][4];
      if (mask1) {
        for (int c = 0; c < 2; ++c) {
          const int colg = kbase + c * 16 + l15;
          for (int r = 0; r < 4; ++r) {
            const int rowg = q0 + 64 + 4 * (quad * 4 + r) + w;
            p[c][r] = __expf((colg > rowg) ? -10000.f : s1[c][r]);
          }
        }
      } else {
        for (int c = 0; c < 2; ++c)
          for (int r = 0; r < 4; ++r) p[c][r] = __expf(s1[c][r]);
      }
      for (int r = 0; r < 4; ++r) l_part[1][r] += p[0][r] + p[1][r];
      for (int c = 0; c < 2; ++c)
        for (int r = 0; r < 4; ++r)
          pw[(16 + quad * 4 + r) * 40 + c * 16 + l15] = (bf16)p[c][r];
    }

    bf16x8 af0, af1;
    if (do0) af0 = *(const bf16x8*)(&Pl[w * 1280 + l15 * 40 + quad * 8]);
    af1 = *(const bf16x8*)(&Pl[w * 1280 + (16 + l15) * 40 + quad * 8]);
    for (int t = 0; t < 8; ++t) {
      bf16x8 vfrag = *(const bf16x8*)(&Vl[nb][(t * 64 + lane) * 8]);
      if (do0) acc_o[0][t] = MFMA16(af0, vfrag, acc_o[0][t]);
      acc_o[1][t] = MFMA16(af1, vfrag, acc_o[1][t]);
    }

    __syncthreads();
  }

  if (u < 4) {
    // direct: full k-range in this block -> normalized final write
    for (int m = 0; m < 2; ++m) {
      float rl[4];
      for (int r = 0; r < 4; ++r) {
        float l = l_part[m][r];
        for (int off = 1; off < 16; off <<= 1) l += __shfl_xor(l, off);
        rl[r] = 1.0f / l;
      }
      for (int r = 0; r < 4; ++r) {
        const int rowg = q0 + m * 64 + 4 * (quad * 4 + r) + w;
        float* op = out + ((size_t)(b * Ss + rowg) * Hh + h) * Dd + l15;
        for (int t = 0; t < 8; ++t) op[t * 16] = acc_o[m][t][r] * rl[r];
      }
    }
  } else {
    const int slot = bh * 36 + (u - 4);
    bf16* po = PO + (size_t)slot * 16384;
    float* pl = PL + (size_t)slot * 128;
    for (int m = 0; m < 2; ++m) {
      for (int r = 0; r < 4; ++r) {
        float l = l_part[m][r];
        for (int off = 1; off < 16; off <<= 1) l += __shfl_xor(l, off);
        if (l15 == 0) pl[m * 64 + 4 * (quad * 4 + r) + w] = l;
      }
      for (int r = 0; r < 4; ++r) {
        const int rloc = m * 64 + 4 * (quad * 4 + r) + w;
        bf16* pp = po + rloc * 128 + l15;
        for (int t = 0; t < 8; ++t) pp[t * 16] = (bf16)acc_o[m][t][r];
      }
    }
  }
}

// ---------------------------------------------------------------------------
// Kernel 3: merge 2-4 partials per (bh, qt>=4) and normalize.
// ---------------------------------------------------------------------------
__global__ __launch_bounds__(256) void reduce_merge(const bf16* __restrict__ PO,
                                                    const float* __restrict__ PL,
                                                    float* __restrict__ out) {
  const int qt = 4 + blockIdx.x;
  const int bh = blockIdx.y;
  const int b = bh >> 4, h = bh & 15;
  const int s0 = bh * 36 + RS0[blockIdx.x];
  const int nch = RN[blockIdx.x];
  const int tid = threadIdx.x;

  __shared__ float linv[128];
  if (tid < 128) {
    float l = 0.f;
    for (int c = 0; c < nch; ++c) l += PL[(size_t)(s0 + c) * 128 + tid];
    linv[tid] = 1.0f / l;
  }
  __syncthreads();

  const int q0 = qt * 128;
  for (int t = 0; t < 32; ++t) {
    const int idx2 = t * 256 + tid;   // pair index; elem = idx2*2
    const int row = idx2 >> 6;
    const int d = (idx2 & 63) * 2;
    float v0 = 0.f, v1 = 0.f;
    for (int c = 0; c < nch; ++c) {
      const bf16* p = PO + (size_t)(s0 + c) * 16384 + row * 128 + d;
      v0 += (float)p[0];
      v1 += (float)p[1];
    }
    float* op = out + ((size_t)(b * Ss + q0 + row) * Hh + h) * Dd + d;
    const float rl = linv[row];
    op[0] = v0 * rl;
    op[1] = v1 * rl;
  }
}

// ---------------------------------------------------------------------------
// Fallback mono kernel (round-4 behavior) if ws is too small for partials.
// ---------------------------------------------------------------------------
__global__ __launch_bounds__(256, 3) void attn_fwd_mono(const bf16* __restrict__ QP,
                                                        const bf16* __restrict__ KP,
                                                        const bf16* __restrict__ VP,
                                                        float* __restrict__ out) {
  __shared__ bf16 Kl[2][4096];
  __shared__ bf16 Vl[2][4096];
  __shared__ bf16 Pl[4 * 32 * 40];

  const int tid = threadIdx.x;
  const int w = tid >> 6, lane = tid & 63, quad = lane >> 4, l15 = lane & 15;
  const int qt = (gridDim.x - 1) - blockIdx.x;
  const int bh = blockIdx.y;
  const int b = bh >> 4, h = bh & 15;
  const int q0 = qt * 128;

  bf16x8 qf[2][4];
  for (int m = 0; m < 2; ++m) {
    const bf16* qp = QP + (size_t)(bh * 32 + 2 * qt + m) * 8192;
    for (int kk = 0; kk < 4; ++kk)
      qf[m][kk] = *(const bf16x8*)(qp + (size_t)(((w * 4 + kk) * 4 + quad) * 16 + l15) * 8);
  }

  floatx4 acc_o[2][8];
  for (int m = 0; m < 2; ++m)
    for (int t = 0; t < 8; ++t) acc_o[m][t] = (floatx4){0.f, 0.f, 0.f, 0.f};
  float l_part[2][4] = {{0.f, 0.f, 0.f, 0.f}, {0.f, 0.f, 0.f, 0.f}};

  const int ntiles = 4 * qt + 4;
  const size_t bh64 = (size_t)bh * 64;
  bf16* pw = &Pl[w * 1280];

  auto stage = [&](int kt, int nb) {
    const bf16* kblob = KP + (bh64 + kt) * 4096;
    const bf16* vblob = VP + (bh64 + kt) * 4096;
    if (w < 2) {
      for (int i = 0; i < 4; ++i) {
        const int g = w * 4 + i;
        cp1k(kblob + g * 512, &Kl[nb][g * 512], lane);
      }
    } else {
      for (int i = 0; i < 4; ++i) {
        const int g = (w - 2) * 4 + i;
        cp1k(vblob + g * 512, &Vl[nb][g * 512], lane);
      }
    }
  };

  stage(0, 0);
  __syncthreads();

  for (int kt = 0; kt < ntiles; ++kt) {
    const int nb = kt & 1;
    if (kt + 1 < ntiles) stage(kt + 1, nb ^ 1);

    const bool do0 = (kt <= 4 * qt + 1);
    const bool mask0 = (kt >= 4 * qt);
    const bool mask1 = (kt >= 4 * qt + 2);
    const int kbase = kt * 32;

    floatx4 s0[2], s1[2];
    s0[0] = s0[1] = s1[0] = s1[1] = (floatx4){0.f, 0.f, 0.f, 0.f};
    for (int c = 0; c < 2; ++c)
      for (int kk = 0; kk < 4; ++kk) {
        bf16x8 bfrag = *(const bf16x8*)(&Kl[nb][((c * 4 + kk) * 64 + lane) * 8]);
        if (do0) s0[c] = MFMA16(qf[0][kk], bfrag, s0[c]);
        s1[c] = MFMA16(qf[1][kk], bfrag, s1[c]);
      }

    if (do0) {
      float p[2][4];
      if (mask0) {
        for (int c = 0; c < 2; ++c) {
          const int colg = kbase + c * 16 + l15;
          for (int r = 0; r < 4; ++r) {
            const int rowg = q0 + 4 * (quad * 4 + r) + w;
            p[c][r] = __expf((colg > rowg) ? -10000.f : s0[c][r]);
          }
        }
      } else {
        for (int c = 0; c < 2; ++c)
          for (int r = 0; r < 4; ++r) p[c][r] = __expf(s0[c][r]);
      }
      for (int r = 0; r < 4; ++r) l_part[0][r] += p[0][r] + p[1][r];
      for (int c = 0; c < 2; ++c)
        for (int r = 0; r < 4; ++r)
          pw[(quad * 4 + r) * 40 + c * 16 + l15] = (bf16)p[c][r];
    }
    {
      float p[2][4];
      if (mask1) {
        for (int c = 0; c < 2; ++c) {
          const int colg = kbase + c * 16 + l15;
          for (int r = 0; r < 4; ++r) {
            const int rowg = q0 + 64 + 4 * (quad * 4 + r) + w;
            p[c][r] = __expf((colg > rowg) ? -10000.f : s1[c][r]);
          }
        }
      } else {
        for (int c = 0; c < 2; ++c)
          for (int r = 0; r < 4; ++r) p[c][r] = __expf(s1[c][r]);
      }
      for (int r = 0; r < 4; ++r) l_part[1][r] += p[0][r] + p[1][r];
      for (int c = 0; c < 2; ++c)
        for (int r = 0; r < 4; ++r)
          pw[(16 + quad * 4 + r) * 40 + c * 16 + l15] = (bf16)p[c][r];
    }

    bf16x8 af0, af1;
    if (do0) af0 = *(const bf16x8*)(&Pl[w * 1280 + l15 * 40 + quad * 8]);
    af1 = *(const bf16x8*)(&Pl[w * 1280 + (16 + l15) * 40 + quad * 8]);
    for (int t = 0; t < 8; ++t) {
      bf16x8 vfrag = *(const bf16x8*)(&Vl[nb][(t * 64 + lane) * 8]);
      if (do0) acc_o[0][t] = MFMA16(af0, vfrag, acc_o[0][t]);
      acc_o[1][t] = MFMA16(af1, vfrag, acc_o[1][t]);
    }

    __syncthreads();
  }

  for (int m = 0; m < 2; ++m) {
    float rl[4];
    for (int r = 0; r < 4; ++r) {
      float l = l_part[m][r];
      for (int off = 1; off < 16; off <<= 1) l += __shfl_xor(l, off);
      rl[r] = 1.0f / l;
    }
    for (int r = 0; r < 4; ++r) {
      const int rowg = q0 + m * 64 + 4 * (quad * 4 + r) + w;
      float* op = out + ((size_t)(b * Ss + rowg) * Hh + h) * Dd + l15;
      for (int t = 0; t < 8; ++t) op[t * 16] = acc_o[m][t][r] * rl[r];
    }
  }
}

extern "C" void kernel_launch(void* const* d_in, const int* in_sizes, int n_in,
                              void* d_out, int out_size, void* d_ws, size_t ws_size,
                              hipStream_t stream) {
  const float* qkv = (const float*)d_in[0];
  float* out = (float*)d_out;
  char* ws = (char*)d_ws;
  bf16* QP = (bf16*)ws;                            // 16 MB
  bf16* KP = (bf16*)(ws + (size_t)16 * 1024 * 1024);  // 16 MB
  bf16* VP = (bf16*)(ws + (size_t)32 * 1024 * 1024);  // 16 MB
  bf16* PO = (bf16*)(ws + (size_t)48 * 1024 * 1024);  // 1152 * 32 KB = 36.86 MB
  float* PL = (float*)(ws + (size_t)48 * 1024 * 1024 + (size_t)1152 * 32768);  // 576 KB

  const size_t need = (size_t)48 * 1024 * 1024 + (size_t)1152 * 32768 + (size_t)1152 * 512;

  prep_pack<<<dim3(32, 32), 256, 0, stream>>>(qkv, QP, KP, VP);
  if (ws_size >= need) {
    attn_fwd_s<<<dim3(40, 32), 256, 0, stream>>>(QP, KP, VP, out, PO, PL);
    reduce_merge<<<dim3(12, 32), 256, 0, stream>>>(PO, PL, out);
  } else {
    attn_fwd_mono<<<dim3(16, 32), 256, 0, stream>>>(QP, KP, VP, out);
  }
}

// Round 6
// 230.976 us; speedup vs baseline: 1.1248x; 1.1248x over previous
//
#include <hip/hip_runtime.h>
#include <hip/hip_bf16.h>
#include <math.h>

typedef __bf16 bf16;
typedef bf16 bf16x8 __attribute__((ext_vector_type(8)));
typedef float floatx4 __attribute__((ext_vector_type(4)));

#define MFMA16(a, b, c) __builtin_amdgcn_mfma_f32_16x16x32_bf16(a, b, c, 0, 0, 0)

constexpr int Bb = 2, Ss = 2048, Hh = 16, Dd = 128;
constexpr float SCALE = 0.08838834764831845f;  // 1/sqrt(128), folded into Q

// Split-K schedule: per bh, 40 units. qt<4 direct; qt>=4 split into 2-4 chunks.
__constant__ int U_QT[40] = {0,1,2,3, 4,4, 5,5, 6,6, 7,7, 8,8,8, 9,9,9, 10,10,10,
                             11,11,11, 12,12,12,12, 13,13,13,13, 14,14,14,14, 15,15,15,15};
__constant__ int U_S[40]  = {0,0,0,0, 0,10, 0,12, 0,14, 0,16, 0,12,24, 0,14,27, 0,15,30,
                             0,16,32, 0,13,26,39, 0,14,28,42, 0,15,30,45, 0,16,32,48};
__constant__ int U_E[40]  = {4,8,12,16, 10,20, 12,24, 14,28, 16,32, 12,24,36, 14,27,40,
                             15,30,44, 16,32,48, 13,26,39,52, 14,28,42,56, 15,30,45,60,
                             16,32,48,64};
__constant__ int RS0[12] = {0,2,4,6,8,11,14,17,20,24,28,32};
__constant__ int RN[12]  = {2,2,2,2,3,3,3,3,4,4,4,4};

// ---------------------------------------------------------------------------
// Kernel 1: pack qkv (fp32) -> MFMA-fragment-ordered bf16 blobs.
// 1D grid 1024: bh = i&31 (XCD-local per bh), qt = i>>5.
// ---------------------------------------------------------------------------
__global__ __launch_bounds__(256) void prep_pack(const float* __restrict__ qkv,
                                                 bf16* __restrict__ QP,
                                                 bf16* __restrict__ KP,
                                                 bf16* __restrict__ VP) {
  __shared__ bf16 Vt[64 * 136];

  const int tid = threadIdx.x;
  const int w = tid >> 6, lane = tid & 63, quad = lane >> 4, l15 = lane & 15;
  const int bh = blockIdx.x & 31, qt = blockIdx.x >> 5;
  const int b = bh >> 4, h = bh & 15;
  const int q0 = qt * 64;
  const size_t rs = (size_t)3 * Hh * Dd;
  const float* base = qkv + (size_t)b * Ss * rs + (size_t)h * Dd;

  for (int idx = tid; idx < 64 * 32; idx += 256) {
    const int row = idx >> 5;
    const int c4 = (idx & 31) << 2;
    const float* p = base + (size_t)(q0 + row) * rs + 2 * Hh * Dd + c4;
    float4 x = *(const float4*)p;
    bf16* d = Vt + row * 136 + c4;
    d[0] = (bf16)x.x; d[1] = (bf16)x.y; d[2] = (bf16)x.z; d[3] = (bf16)x.w;
  }

  {
    bf16* blob = QP + (size_t)(bh * 32 + qt) * 8192;
    const float* src = base + (size_t)(q0 + 4 * l15 + w) * rs;
    for (int kk = 0; kk < 4; ++kk) {
      const float* s8 = src + kk * 32 + quad * 8;
      float4 x0 = *(const float4*)s8, x1 = *(const float4*)(s8 + 4);
      bf16x8 f;
      f[0] = (bf16)(x0.x * SCALE); f[1] = (bf16)(x0.y * SCALE);
      f[2] = (bf16)(x0.z * SCALE); f[3] = (bf16)(x0.w * SCALE);
      f[4] = (bf16)(x1.x * SCALE); f[5] = (bf16)(x1.y * SCALE);
      f[6] = (bf16)(x1.z * SCALE); f[7] = (bf16)(x1.w * SCALE);
      *(bf16x8*)(blob + (size_t)(((w * 4 + kk) * 4 + quad) * 16 + l15) * 8) = f;
    }
  }

  const int ktg = qt * 2 + (w >> 1);
  {
    const int c = w & 1;
    bf16* blob = KP + (size_t)(bh * 64 + ktg) * 4096;
    const float* src = base + (size_t)(ktg * 32 + c * 16 + l15) * rs + Hh * Dd;
    for (int kk = 0; kk < 4; ++kk) {
      const float* s8 = src + kk * 32 + quad * 8;
      float4 x0 = *(const float4*)s8, x1 = *(const float4*)(s8 + 4);
      bf16x8 f;
      f[0] = (bf16)x0.x; f[1] = (bf16)x0.y; f[2] = (bf16)x0.z; f[3] = (bf16)x0.w;
      f[4] = (bf16)x1.x; f[5] = (bf16)x1.y; f[6] = (bf16)x1.z; f[7] = (bf16)x1.w;
      *(bf16x8*)(blob + (size_t)(((c * 4 + kk) * 4 + quad) * 16 + l15) * 8) = f;
    }
  }

  __syncthreads();

  {
    bf16* blob = VP + (size_t)(bh * 64 + ktg) * 4096;
    const int kloc = (w >> 1) * 32;
    for (int ti = 0; ti < 4; ++ti) {
      const int t = (w & 1) * 4 + ti;
      const int d = t * 16 + l15;
      bf16x8 f;
      for (int j = 0; j < 8; ++j) f[j] = Vt[(kloc + quad * 8 + j) * 136 + d];
      *(bf16x8*)(blob + (size_t)((t * 4 + quad) * 16 + l15) * 8) = f;
    }
  }
}

__device__ __forceinline__ void cp1k(const bf16* src, bf16* dst, int lane) {
  __builtin_amdgcn_global_load_lds(
      (__attribute__((address_space(1))) void*)(src + lane * 8),
      (__attribute__((address_space(3))) void*)dst, 16, 0, 0);
}

// ---------------------------------------------------------------------------
// Kernel 2 (split-K): 1D grid 1280; bh = i&31 (XCD-local), u = i>>5.
// ---------------------------------------------------------------------------
__global__ __launch_bounds__(256, 3) void attn_fwd_s(const bf16* __restrict__ QP,
                                                     const bf16* __restrict__ KP,
                                                     const bf16* __restrict__ VP,
                                                     float* __restrict__ out,
                                                     bf16* __restrict__ PO,
                                                     float* __restrict__ PL) {
  __shared__ bf16 Kl[2][4096];
  __shared__ bf16 Vl[2][4096];
  __shared__ bf16 Pl[4 * 32 * 40];

  const int tid = threadIdx.x;
  const int w = tid >> 6, lane = tid & 63, quad = lane >> 4, l15 = lane & 15;
  const int bh = blockIdx.x & 31;
  const int u = blockIdx.x >> 5;
  const int b = bh >> 4, h = bh & 15;
  const int qt = U_QT[u];
  const int ks = U_S[u], ke = U_E[u];
  const int q0 = qt * 128;

  bf16x8 qf[2][4];
  for (int m = 0; m < 2; ++m) {
    const bf16* qp = QP + (size_t)(bh * 32 + 2 * qt + m) * 8192;
    for (int kk = 0; kk < 4; ++kk)
      qf[m][kk] = *(const bf16x8*)(qp + (size_t)(((w * 4 + kk) * 4 + quad) * 16 + l15) * 8);
  }

  floatx4 acc_o[2][8];
  for (int m = 0; m < 2; ++m)
    for (int t = 0; t < 8; ++t) acc_o[m][t] = (floatx4){0.f, 0.f, 0.f, 0.f};
  float l_part[2][4] = {{0.f, 0.f, 0.f, 0.f}, {0.f, 0.f, 0.f, 0.f}};

  const size_t bh64 = (size_t)bh * 64;
  bf16* pw = &Pl[w * 1280];

  auto stage = [&](int kt, int nb) {
    const bf16* kblob = KP + (bh64 + kt) * 4096;
    const bf16* vblob = VP + (bh64 + kt) * 4096;
    if (w < 2) {
      for (int i = 0; i < 4; ++i) {
        const int g = w * 4 + i;
        cp1k(kblob + g * 512, &Kl[nb][g * 512], lane);
      }
    } else {
      for (int i = 0; i < 4; ++i) {
        const int g = (w - 2) * 4 + i;
        cp1k(vblob + g * 512, &Vl[nb][g * 512], lane);
      }
    }
  };

  stage(ks, 0);
  __syncthreads();

  for (int it = 0, kt = ks; kt < ke; ++kt, ++it) {
    const int nb = it & 1;
    if (kt + 1 < ke) stage(kt + 1, nb ^ 1);

    const bool do0 = (kt <= 4 * qt + 1);
    const bool mask0 = (kt >= 4 * qt);
    const bool mask1 = (kt >= 4 * qt + 2);
    const int kbase = kt * 32;

    floatx4 s0[2], s1[2];
    s0[0] = s0[1] = s1[0] = s1[1] = (floatx4){0.f, 0.f, 0.f, 0.f};
    for (int c = 0; c < 2; ++c)
      for (int kk = 0; kk < 4; ++kk) {
        bf16x8 bfrag = *(const bf16x8*)(&Kl[nb][((c * 4 + kk) * 64 + lane) * 8]);
        if (do0) s0[c] = MFMA16(qf[0][kk], bfrag, s0[c]);
        s1[c] = MFMA16(qf[1][kk], bfrag, s1[c]);
      }

    if (do0) {
      float p[2][4];
      if (mask0) {
        for (int c = 0; c < 2; ++c) {
          const int colg = kbase + c * 16 + l15;
          for (int r = 0; r < 4; ++r) {
            const int rowg = q0 + 4 * (quad * 4 + r) + w;
            p[c][r] = __expf((colg > rowg) ? -10000.f : s0[c][r]);
          }
        }
      } else {
        for (int c = 0; c < 2; ++c)
          for (int r = 0; r < 4; ++r) p[c][r] = __expf(s0[c][r]);
      }
      for (int r = 0; r < 4; ++r) l_part[0][r] += p[0][r] + p[1][r];
      for (int c = 0; c < 2; ++c)
        for (int r = 0; r < 4; ++r)
          pw[(quad * 4 + r) * 40 + c * 16 + l15] = (bf16)p[c][r];
    }
    {
      float p[2][4];
      if (mask1) {
        for (int c = 0; c < 2; ++c) {
          const int colg = kbase + c * 16 + l15;
          for (int r = 0; r < 4; ++r) {
            const int rowg = q0 + 64 + 4 * (quad * 4 + r) + w;
            p[c][r] = __expf((colg > rowg) ? -10000.f : s1[c][r]);
          }
        }
      } else {
        for (int c = 0; c < 2; ++c)
          for (int r = 0; r < 4; ++r) p[c][r] = __expf(s1[c][r]);
      }
      for (int r = 0; r < 4; ++r) l_part[1][r] += p[0][r] + p[1][r];
      for (int c = 0; c < 2; ++c)
        for (int r = 0; r < 4; ++r)
          pw[(16 + quad * 4 + r) * 40 + c * 16 + l15] = (bf16)p[c][r];
    }

    bf16x8 af0, af1;
    if (do0) af0 = *(const bf16x8*)(&Pl[w * 1280 + l15 * 40 + quad * 8]);
    af1 = *(const bf16x8*)(&Pl[w * 1280 + (16 + l15) * 40 + quad * 8]);
    for (int t = 0; t < 8; ++t) {
      bf16x8 vfrag = *(const bf16x8*)(&Vl[nb][(t * 64 + lane) * 8]);
      if (do0) acc_o[0][t] = MFMA16(af0, vfrag, acc_o[0][t]);
      acc_o[1][t] = MFMA16(af1, vfrag, acc_o[1][t]);
    }

    __syncthreads();
  }

  if (u < 4) {
    for (int m = 0; m < 2; ++m) {
      float rl[4];
      for (int r = 0; r < 4; ++r) {
        float l = l_part[m][r];
        for (int off = 1; off < 16; off <<= 1) l += __shfl_xor(l, off);
        rl[r] = 1.0f / l;
      }
      for (int r = 0; r < 4; ++r) {
        const int rowg = q0 + m * 64 + 4 * (quad * 4 + r) + w;
        float* op = out + ((size_t)(b * Ss + rowg) * Hh + h) * Dd + l15;
        for (int t = 0; t < 8; ++t) op[t * 16] = acc_o[m][t][r] * rl[r];
      }
    }
  } else {
    const int slot = bh * 36 + (u - 4);
    bf16* po = PO + (size_t)slot * 16384;
    float* pl = PL + (size_t)slot * 128;
    bf16* Ol = &Kl[0][0];  // 16 KB staging: [64 rows][128 d], Kl/Vl dead now
    for (int m = 0; m < 2; ++m) {
      for (int r = 0; r < 4; ++r) {
        float l = l_part[m][r];
        for (int off = 1; off < 16; off <<= 1) l += __shfl_xor(l, off);
        if (l15 == 0) pl[m * 64 + 4 * (quad * 4 + r) + w] = l;
      }
      __syncthreads();
      for (int r = 0; r < 4; ++r) {
        const int rl = 4 * (quad * 4 + r) + w;
        bf16* op = Ol + rl * 128 + l15;
        for (int t = 0; t < 8; ++t) op[t * 16] = (bf16)acc_o[m][t][r];
      }
      __syncthreads();
      for (int k = 0; k < 4; ++k) {
        bf16x8 v = *(const bf16x8*)(Ol + k * 2048 + tid * 8);
        *(bf16x8*)(po + m * 8192 + k * 2048 + tid * 8) = v;
      }
    }
  }
}

// ---------------------------------------------------------------------------
// Kernel 3: merge 2-4 partials per (bh, qt>=4), normalize. Vectorized.
// 1D grid 384: bh = i&31 (XCD-local, partials still warm in L2), j = i>>5.
// ---------------------------------------------------------------------------
__global__ __launch_bounds__(512) void reduce_merge(const bf16* __restrict__ PO,
                                                    const float* __restrict__ PL,
                                                    float* __restrict__ out) {
  const int bh = blockIdx.x & 31;
  const int j = blockIdx.x >> 5;  // qt = 4 + j
  const int b = bh >> 4, h = bh & 15;
  const int s0 = bh * 36 + RS0[j];
  const int nch = RN[j];
  const int tid = threadIdx.x;
  const int row = tid >> 2;        // 0..127
  const int d0 = (tid & 3) << 5;   // 0/32/64/96

  float l = 0.f;
  for (int c = 0; c < nch; ++c) l += PL[(size_t)(s0 + c) * 128 + row];
  const float rl = 1.0f / l;

  float acc[32];
#pragma unroll
  for (int e = 0; e < 32; ++e) acc[e] = 0.f;
  for (int c = 0; c < nch; ++c) {
    const bf16* p = PO + (size_t)(s0 + c) * 16384 + row * 128 + d0;
#pragma unroll
    for (int k = 0; k < 4; ++k) {
      bf16x8 v = *(const bf16x8*)(p + k * 8);
#pragma unroll
      for (int e = 0; e < 8; ++e) acc[k * 8 + e] += (float)v[e];
    }
  }

  const int q0 = (4 + j) * 128;
  float* op = out + ((size_t)(b * Ss + q0 + row) * Hh + h) * Dd + d0;
#pragma unroll
  for (int k = 0; k < 8; ++k) {
    float4 o;
    o.x = acc[k * 4 + 0] * rl;
    o.y = acc[k * 4 + 1] * rl;
    o.z = acc[k * 4 + 2] * rl;
    o.w = acc[k * 4 + 3] * rl;
    *(float4*)(op + k * 4) = o;
  }
}

// ---------------------------------------------------------------------------
// Fallback mono kernel if ws is too small for partials.
// ---------------------------------------------------------------------------
__global__ __launch_bounds__(256, 3) void attn_fwd_mono(const bf16* __restrict__ QP,
                                                        const bf16* __restrict__ KP,
                                                        const bf16* __restrict__ VP,
                                                        float* __restrict__ out) {
  __shared__ bf16 Kl[2][4096];
  __shared__ bf16 Vl[2][4096];
  __shared__ bf16 Pl[4 * 32 * 40];

  const int tid = threadIdx.x;
  const int w = tid >> 6, lane = tid & 63, quad = lane >> 4, l15 = lane & 15;
  const int qt = (gridDim.x - 1) - blockIdx.x;
  const int bh = blockIdx.y;
  const int b = bh >> 4, h = bh & 15;
  const int q0 = qt * 128;

  bf16x8 qf[2][4];
  for (int m = 0; m < 2; ++m) {
    const bf16* qp = QP + (size_t)(bh * 32 + 2 * qt + m) * 8192;
    for (int kk = 0; kk < 4; ++kk)
      qf[m][kk] = *(const bf16x8*)(qp + (size_t)(((w * 4 + kk) * 4 + quad) * 16 + l15) * 8);
  }

  floatx4 acc_o[2][8];
  for (int m = 0; m < 2; ++m)
    for (int t = 0; t < 8; ++t) acc_o[m][t] = (floatx4){0.f, 0.f, 0.f, 0.f};
  float l_part[2][4] = {{0.f, 0.f, 0.f, 0.f}, {0.f, 0.f, 0.f, 0.f}};

  const int ntiles = 4 * qt + 4;
  const size_t bh64 = (size_t)bh * 64;
  bf16* pw = &Pl[w * 1280];

  auto stage = [&](int kt, int nb) {
    const bf16* kblob = KP + (bh64 + kt) * 4096;
    const bf16* vblob = VP + (bh64 + kt) * 4096;
    if (w < 2) {
      for (int i = 0; i < 4; ++i) {
        const int g = w * 4 + i;
        cp1k(kblob + g * 512, &Kl[nb][g * 512], lane);
      }
    } else {
      for (int i = 0; i < 4; ++i) {
        const int g = (w - 2) * 4 + i;
        cp1k(vblob + g * 512, &Vl[nb][g * 512], lane);
      }
    }
  };

  stage(0, 0);
  __syncthreads();

  for (int kt = 0; kt < ntiles; ++kt) {
    const int nb = kt & 1;
    if (kt + 1 < ntiles) stage(kt + 1, nb ^ 1);

    const bool do0 = (kt <= 4 * qt + 1);
    const bool mask0 = (kt >= 4 * qt);
    const bool mask1 = (kt >= 4 * qt + 2);
    const int kbase = kt * 32;

    floatx4 s0[2], s1[2];
    s0[0] = s0[1] = s1[0] = s1[1] = (floatx4){0.f, 0.f, 0.f, 0.f};
    for (int c = 0; c < 2; ++c)
      for (int kk = 0; kk < 4; ++kk) {
        bf16x8 bfrag = *(const bf16x8*)(&Kl[nb][((c * 4 + kk) * 64 + lane) * 8]);
        if (do0) s0[c] = MFMA16(qf[0][kk], bfrag, s0[c]);
        s1[c] = MFMA16(qf[1][kk], bfrag, s1[c]);
      }

    if (do0) {
      float p[2][4];
      if (mask0) {
        for (int c = 0; c < 2; ++c) {
          const int colg = kbase + c * 16 + l15;
          for (int r = 0; r < 4; ++r) {
            const int rowg = q0 + 4 * (quad * 4 + r) + w;
            p[c][r] = __expf((colg > rowg) ? -10000.f : s0[c][r]);
          }
        }
      } else {
        for (int c = 0; c < 2; ++c)
          for (int r = 0; r < 4; ++r) p[c][r] = __expf(s0[c][r]);
      }
      for (int r = 0; r < 4; ++r) l_part[0][r] += p[0][r] + p[1][r];
      for (int c = 0; c < 2; ++c)
        for (int r = 0; r < 4; ++r)
          pw[(quad * 4 + r) * 40 + c * 16 + l15] = (bf16)p[c][r];
    }
    {
      float p[2][4];
      if (mask1) {
        for (int c = 0; c < 2; ++c) {
          const int colg = kbase + c * 16 + l15;
          for (int r = 0; r < 4; ++r) {
            const int rowg = q0 + 64 + 4 * (quad * 4 + r) + w;
            p[c][r] = __expf((colg > rowg) ? -10000.f : s1[c][r]);
          }
        }
      } else {
        for (int c = 0; c < 2; ++c)
          for (int r = 0; r < 4; ++r) p[c][r] = __expf(s1[c][r]);
      }
      for (int r = 0; r < 4; ++r) l_part[1][r] += p[0][r] + p[1][r];
      for (int c = 0; c < 2; ++c)
        for (int r = 0; r < 4; ++r)
          pw[(16 + quad * 4 + r) * 40 + c * 16 + l15] = (bf16)p[c][r];
    }

    bf16x8 af0, af1;
    if (do0) af0 = *(const bf16x8*)(&Pl[w * 1280 + l15 * 40 + quad * 8]);
    af1 = *(const bf16x8*)(&Pl[w * 1280 + (16 + l15) * 40 + quad * 8]);
    for (int t = 0; t < 8; ++t) {
      bf16x8 vfrag = *(const bf16x8*)(&Vl[nb][(t * 64 + lane) * 8]);
      if (do0) acc_o[0][t] = MFMA16(af0, vfrag, acc_o[0][t]);
      acc_o[1][t] = MFMA16(af1, vfrag, acc_o[1][t]);
    }

    __syncthreads();
  }

  for (int m = 0; m < 2; ++m) {
    float rl[4];
    for (int r = 0; r < 4; ++r) {
      float l = l_part[m][r];
      for (int off = 1; off < 16; off <<= 1) l += __shfl_xor(l, off);
      rl[r] = 1.0f / l;
    }
    for (int r = 0; r < 4; ++r) {
      const int rowg = q0 + m * 64 + 4 * (quad * 4 + r) + w;
      float* op = out + ((size_t)(b * Ss + rowg) * Hh + h) * Dd + l15;
      for (int t = 0; t < 8; ++t) op[t * 16] = acc_o[m][t][r] * rl[r];
    }
  }
}

extern "C" void kernel_launch(void* const* d_in, const int* in_sizes, int n_in,
                              void* d_out, int out_size, void* d_ws, size_t ws_size,
                              hipStream_t stream) {
  const float* qkv = (const float*)d_in[0];
  float* out = (float*)d_out;
  char* ws = (char*)d_ws;
  bf16* QP = (bf16*)ws;                               // 16 MB
  bf16* KP = (bf16*)(ws + (size_t)16 * 1024 * 1024);  // 16 MB
  bf16* VP = (bf16*)(ws + (size_t)32 * 1024 * 1024);  // 16 MB
  bf16* PO = (bf16*)(ws + (size_t)48 * 1024 * 1024);  // 1152 * 32 KB
  float* PL = (float*)(ws + (size_t)48 * 1024 * 1024 + (size_t)1152 * 32768);

  const size_t need = (size_t)48 * 1024 * 1024 + (size_t)1152 * 32768 + (size_t)1152 * 512;

  prep_pack<<<dim3(1024), 256, 0, stream>>>(qkv, QP, KP, VP);
  if (ws_size >= need) {
    attn_fwd_s<<<dim3(1280), 256, 0, stream>>>(QP, KP, VP, out, PO, PL);
    reduce_merge<<<dim3(384), 512, 0, stream>>>(PO, PL, out);
  } else {
    attn_fwd_mono<<<dim3(16, 32), 256, 0, stream>>>(QP, KP, VP, out);
  }
}